// Round 8
// baseline (216.044 us; speedup 1.0000x reference)
//
#include <hip/hip_runtime.h>
#include <hip/hip_bf16.h>

typedef __attribute__((ext_vector_type(8))) short short8;
typedef __attribute__((ext_vector_type(4))) short short4_;
typedef __attribute__((ext_vector_type(4))) float f32x4;
typedef __attribute__((ext_vector_type(16))) float f32x16;
typedef unsigned short u16;

#define L2E 1.4426950408889634f

__device__ __forceinline__ u16 f2bf(float x) {
    union { float f; unsigned u; } v; v.f = x;
    return (u16)((v.u + 0x7FFFu + ((v.u >> 16) & 1u)) >> 16);
}

__device__ __forceinline__ int cvtpk(float lo, float hi) {
    int r;
    asm("v_cvt_pk_bf16_f32 %0, %1, %2" : "=v"(r) : "v"(lo), "v"(hi));
    return r;
}

// a' = {a.lanes0-31, b.lanes0-31}; b' = {a.lanes32-63, b.lanes32-63}
__device__ __forceinline__ void plswap(int& a, int& b) {
    asm volatile("v_permlane32_swap_b32 %0, %1" : "+v"(a), "+v"(b));
}

// ---------------------------------------------------------------------------
// Workspace layout (bytes):
//  wtq   @ 0        : 64*1024*2   = 131072
//  wtkv  @ 131072   : 128*1024*2  = 262144  (rows 0-63 = Wk^T, 64-127 = Wv^T)
//  Qb    @ 393216   : 4*2048*64*2 = 1048576 (scale 0.125 + bias folded)
//  Kb    @ 1441792  : 4*4096*64*2 = 2097152
//  Vtb   @ 3538944  : 4*64*4096*2 = 2097152 ([b][d][s])
//  OpT   @ 5636096  : NS*4*64*2048*4        ([ks][b][d][q] partial O^T)
//  Mpart / Lpart after OpT.
// ---------------------------------------------------------------------------
#define WTQ_OFF   0
#define WTKV_OFF  131072
#define Q_OFF     393216
#define K_OFF     1441792
#define VT_OFF    3538944
#define OPT_OFF   5636096

// ---------------------------------------------------------------------------
// prep2: W [1024][64] f32 -> W^T [64][1024] bf16, coalesced via LDS tile.
// (unchanged from R5 — passed)
// ---------------------------------------------------------------------------
__global__ __launch_bounds__(256) void prep2(
    const float* __restrict__ Wq, const float* __restrict__ Wk,
    const float* __restrict__ Wv, u16* __restrict__ wtq, u16* __restrict__ wtkv)
{
    __shared__ u16 tile[64][66];
    const int t = threadIdx.x;
    const int mat = blockIdx.x >> 4, kc = blockIdx.x & 15;
    const float* src = (mat == 0) ? Wq : ((mat == 1) ? Wk : Wv);
    u16* dst = (mat == 0) ? wtq : (wtkv + ((mat == 2) ? 64 * 1024 : 0));
    #pragma unroll
    for (int c = 0; c < 4; ++c) {
        int id = t + c * 256;
        int r = id >> 4, c4 = id & 15;
        float4 v = *(const float4*)(src + (size_t)(kc * 64 + r) * 64 + c4 * 4);
        tile[r][c4 * 4 + 0] = f2bf(v.x);
        tile[r][c4 * 4 + 1] = f2bf(v.y);
        tile[r][c4 * 4 + 2] = f2bf(v.z);
        tile[r][c4 * 4 + 3] = f2bf(v.w);
    }
    __syncthreads();
    int n = t >> 2, kch = t & 3;
    short8 v0, v1;
    #pragma unroll
    for (int j = 0; j < 8; ++j) {
        v0[j] = (short)tile[kch * 16 + j][n];
        v1[j] = (short)tile[kch * 16 + 8 + j][n];
    }
    u16* dp = dst + (size_t)n * 1024 + kc * 64 + kch * 16;
    *(short8*)dp = v0;
    *(short8*)(dp + 8) = v1;
}

// ---------------------------------------------------------------------------
// proj5: barrier-free, LDS-free per-wave projection. Each wave: 16 rows x
// NREP*16 cols. A-fragments loaded DIRECTLY global->VGPR (lane l owns
// row=l&15, k=(l>>4)*8 — exact MFMA A layout, zero duplication); converted
// to bf16 via f2bf (RNE, proj3-proven). W^T bf16 fragments direct from L2.
// No LDS, no global_load_lds, no inline waitcnt: compiler schedules all.
// NREP=8: enc -> K (cols 0-63) + V^T (64-127). NREP=4: dec -> Q.
// ---------------------------------------------------------------------------
template<int NREP>
__device__ __forceinline__ void proj5_body(
    const float* __restrict__ A, const u16* __restrict__ W,
    const float* __restrict__ bias0, const float* __restrict__ bias1,
    float scale, u16* __restrict__ out0, u16* __restrict__ Vtb,
    int r0, int l)
{
    const int arow = l & 15, q = l >> 4;
    f32x4 acc[NREP];
    #pragma unroll
    for (int n = 0; n < NREP; ++n) acc[n] = (f32x4){0.f, 0.f, 0.f, 0.f};

    const float* ap = A + (size_t)(r0 + arow) * 1024 + q * 8;
    const u16* wp0 = W + (size_t)arow * 1024 + q * 8;

    #pragma unroll 4
    for (int i = 0; i < 16; ++i) {
        short8 af[2];
        #pragma unroll
        for (int ks = 0; ks < 2; ++ks) {
            f32x4 lo = *(const f32x4*)(ap + i * 64 + ks * 32);
            f32x4 hi = *(const f32x4*)(ap + i * 64 + ks * 32 + 4);
            short8 r;
            r[0] = (short)f2bf(lo[0]); r[1] = (short)f2bf(lo[1]);
            r[2] = (short)f2bf(lo[2]); r[3] = (short)f2bf(lo[3]);
            r[4] = (short)f2bf(hi[0]); r[5] = (short)f2bf(hi[1]);
            r[6] = (short)f2bf(hi[2]); r[7] = (short)f2bf(hi[3]);
            af[ks] = r;
        }
        #pragma unroll
        for (int n = 0; n < NREP; ++n) {
            const u16* wp = wp0 + (size_t)n * 16384 + i * 64;
            short8 w0 = *(const short8*)wp;
            short8 w1 = *(const short8*)(wp + 32);
            acc[n] = __builtin_amdgcn_mfma_f32_16x16x32_bf16(af[0], w0, acc[n], 0, 0, 0);
            acc[n] = __builtin_amdgcn_mfma_f32_16x16x32_bf16(af[1], w1, acc[n], 0, 0, 0);
        }
    }

    // epilogue (wave-local): row = q*4+i, col = n*16+arow
    #pragma unroll
    for (int n = 0; n < NREP; ++n) {
        int col = n * 16 + arow;
        if (NREP == 4 || n < 4) {
            float bv0 = bias0[col];
            #pragma unroll
            for (int i = 0; i < 4; ++i) {
                int row = q * 4 + i;
                out0[(size_t)(r0 + row) * 64 + col] = f2bf((acc[n][i] + bv0) * scale);
            }
        } else {
            int d = col - 64;
            float bv1 = bias1[d];
            short4_ pk;
            #pragma unroll
            for (int i = 0; i < 4; ++i) pk[i] = (short)f2bf(acc[n][i] + bv1);
            int bb = r0 >> 12, sbase = (r0 & 4095) + q * 4;
            *(short4_*)(Vtb + (size_t)(bb * 64 + d) * 4096 + sbase) = pk;
        }
    }
}

__global__ __launch_bounds__(256, 2) void proj5(
    const float* __restrict__ enc, const float* __restrict__ dec,
    const u16* __restrict__ wtkv, const u16* __restrict__ wtq,
    const float* __restrict__ bk, const float* __restrict__ bv,
    const float* __restrict__ bq,
    u16* __restrict__ Kb, u16* __restrict__ Vtb, u16* __restrict__ Qb)
{
    const int t = threadIdx.x, l = t & 63, w = t >> 6;
    if (blockIdx.x < 256) {
        int r0 = blockIdx.x * 64 + w * 16;
        proj5_body<8>(enc, wtkv, bk, bv, 1.0f, Kb, Vtb, r0, l);
    } else {
        int r0 = (blockIdx.x - 256) * 64 + w * 16;
        proj5_body<4>(dec, wtq, bq, bq, 0.125f, Qb, (u16*)nullptr, r0, l);
    }
}

// ---------------------------------------------------------------------------
// attn3<NS>: swapped-operand flash attention, no LDS, 32x32x16 MFMA.
// (unchanged from R5 — passed)
// ---------------------------------------------------------------------------
template<int NS>
__global__ __launch_bounds__(256, 2) void attn3(
    const u16* __restrict__ Qb, const u16* __restrict__ Kb,
    const u16* __restrict__ Vtb, float* __restrict__ OpT,
    float* __restrict__ Mpart, float* __restrict__ Lpart)
{
    constexpr int SPAN = 4096 / NS;
    constexpr int NIT = SPAN / 64;
    const int t = threadIdx.x, l = t & 63, w = t >> 6;
    const int b = blockIdx.y, bz = blockIdx.z;
    const int q0 = (blockIdx.x * 4 + w) * 32;
    const int lq = l & 31, lh = l >> 5;

    short8 qf[4];
    #pragma unroll
    for (int dt = 0; dt < 4; ++dt)
        qf[dt] = *(const short8*)(Qb + (size_t)(b * 2048 + q0 + lq) * 64
                                  + dt * 16 + lh * 8);

    f32x16 o0, o1;
    #pragma unroll
    for (int r = 0; r < 16; ++r) { o0[r] = 0.f; o1[r] = 0.f; }
    float mrun = -INFINITY, lrun = 0.f;

    const size_t kbase = (size_t)b * 4096 * 64;
    const size_t vbase = (size_t)b * 64 * 4096;

    auto LOADT = [&](short8 (&kf)[4], short8 (&vf)[2][2], int kt) {
        #pragma unroll
        for (int dt = 0; dt < 4; ++dt)
            kf[dt] = *(const short8*)(Kb + kbase + (size_t)(kt + lq) * 64
                                      + dt * 16 + lh * 8);
        #pragma unroll
        for (int db = 0; db < 2; ++db)
            #pragma unroll
            for (int kh = 0; kh < 2; ++kh)
                vf[db][kh] = *(const short8*)(Vtb + vbase
                                              + (size_t)(db * 32 + lq) * 4096
                                              + kt + kh * 16 + lh * 8);
    };

    auto COMPUTE = [&](short8 (&kf)[4], short8 (&vf)[2][2]) {
        f32x16 s;
        #pragma unroll
        for (int r = 0; r < 16; ++r) s[r] = 0.f;
        #pragma unroll
        for (int dt = 0; dt < 4; ++dt)
            s = __builtin_amdgcn_mfma_f32_32x32x16_bf16(kf[dt], qf[dt], s, 0, 0, 0);
        float m0 = fmaxf(fmaxf(s[0], s[1]), fmaxf(s[2], s[3]));
        float m1 = fmaxf(fmaxf(s[4], s[5]), fmaxf(s[6], s[7]));
        float m2 = fmaxf(fmaxf(s[8], s[9]), fmaxf(s[10], s[11]));
        float m3 = fmaxf(fmaxf(s[12], s[13]), fmaxf(s[14], s[15]));
        float pm = fmaxf(fmaxf(m0, m1), fmaxf(m2, m3));
        pm = fmaxf(pm, __shfl_xor(pm, 32));
        float mn = fmaxf(mrun, pm);
        float corr = exp2f((mrun - mn) * L2E);
        mrun = mn;
        float nm = -mn * L2E;
        float p[16];
        #pragma unroll
        for (int r = 0; r < 16; ++r) p[r] = exp2f(fmaf(s[r], L2E, nm));
        float rs = ((p[0] + p[1]) + (p[2] + p[3])) + ((p[4] + p[5]) + (p[6] + p[7]))
                 + ((p[8] + p[9]) + (p[10] + p[11])) + ((p[12] + p[13]) + (p[14] + p[15]));
        rs += __shfl_xor(rs, 32);
        lrun = lrun * corr + rs;
        o0 *= corr;
        o1 *= corr;
        short8 pb[2];
        #pragma unroll
        for (int kh = 0; kh < 2; ++kh) {
            int a0 = cvtpk(p[kh * 8 + 0], p[kh * 8 + 1]);
            int b0 = cvtpk(p[kh * 8 + 4], p[kh * 8 + 5]);
            int a1 = cvtpk(p[kh * 8 + 2], p[kh * 8 + 3]);
            int b1 = cvtpk(p[kh * 8 + 6], p[kh * 8 + 7]);
            plswap(a0, b0);
            plswap(a1, b1);
            union { int wd[4]; short8 v; } u;
            u.wd[0] = a0; u.wd[1] = a1; u.wd[2] = b0; u.wd[3] = b1;
            pb[kh] = u.v;
        }
        #pragma unroll
        for (int kh = 0; kh < 2; ++kh) {
            o0 = __builtin_amdgcn_mfma_f32_32x32x16_bf16(vf[0][kh], pb[kh], o0, 0, 0, 0);
            o1 = __builtin_amdgcn_mfma_f32_32x32x16_bf16(vf[1][kh], pb[kh], o1, 0, 0, 0);
        }
    };

    short8 kfA[4], vfA[2][2], kfB[4], vfB[2][2];
    const int kt0 = bz * SPAN;
    LOADT(kfA, vfA, kt0);
    for (int it = 0; it < NIT; ++it) {
        const int kt = kt0 + it * 64;
        LOADT(kfB, vfB, kt + 32);
        COMPUTE(kfA, vfA);
        if (it < NIT - 1) LOADT(kfA, vfA, kt + 64);
        COMPUTE(kfB, vfB);
    }

    const size_t obase = ((size_t)(bz * 4 + b) * 64) * 2048 + q0 + lq;
    #pragma unroll
    for (int r = 0; r < 16; ++r) {
        int drow = (r & 3) + 8 * (r >> 2) + 4 * lh;
        OpT[obase + (size_t)drow * 2048] = o0[r];
        OpT[obase + (size_t)(drow + 32) * 2048] = o1[r];
    }
    if (l < 32) {
        Mpart[bz * 8192 + b * 2048 + q0 + l] = mrun;
        Lpart[bz * 8192 + b * 2048 + q0 + l] = lrun;
    }
}

// ---------------------------------------------------------------------------
// combine3<NS>: merge NS key-splits of O^T, normalize, transpose to O[q][d].
// (unchanged from R5 — passed)
// ---------------------------------------------------------------------------
template<int NS>
__global__ __launch_bounds__(256) void combine3(
    const float* __restrict__ OpT, const float* __restrict__ Mpart,
    const float* __restrict__ Lpart, float* __restrict__ Out)
{
    __shared__ float wsh[NS][32];
    __shared__ float trans[32][72];
    const int t = threadIdx.x;
    const int b = blockIdx.x >> 6;
    const int q0 = (blockIdx.x & 63) * 32;

    if (t < 32) {
        int q = t;
        float m4[NS], M = -INFINITY;
        #pragma unroll
        for (int ks = 0; ks < NS; ++ks) {
            m4[ks] = Mpart[ks * 8192 + b * 2048 + q0 + q];
            M = fmaxf(M, m4[ks]);
        }
        float wv[NS], Lf = 0.f;
        #pragma unroll
        for (int ks = 0; ks < NS; ++ks) {
            wv[ks] = exp2f((m4[ks] - M) * L2E);
            Lf += Lpart[ks * 8192 + b * 2048 + q0 + q] * wv[ks];
        }
        float inv = 1.0f / Lf;
        #pragma unroll
        for (int ks = 0; ks < NS; ++ks) wsh[ks][q] = wv[ks] * inv;
    }
    __syncthreads();
    {
        int d = t >> 2, qc = (t & 3) * 8;
        float a8[8];
        #pragma unroll
        for (int j = 0; j < 8; ++j) a8[j] = 0.f;
        #pragma unroll
        for (int ks = 0; ks < NS; ++ks) {
            const float* p = OpT + (((size_t)(ks * 4 + b)) * 64 + d) * 2048 + q0 + qc;
            f32x4 x = *(const f32x4*)p;
            f32x4 y = *(const f32x4*)(p + 4);
            #pragma unroll
            for (int j = 0; j < 4; ++j) {
                a8[j]     += x[j] * wsh[ks][qc + j];
                a8[4 + j] += y[j] * wsh[ks][qc + 4 + j];
            }
        }
        #pragma unroll
        for (int j = 0; j < 8; ++j) trans[qc + j][d] = a8[j];
    }
    __syncthreads();
    {
        int q = t >> 3, dc = (t & 7) * 8;
        f32x4 x = *(const f32x4*)&trans[q][dc];
        f32x4 y = *(const f32x4*)&trans[q][dc + 4];
        float* dst = Out + ((size_t)(b * 2048 + q0 + q)) * 64 + dc;
        *(f32x4*)dst = x;
        *(f32x4*)(dst + 4) = y;
    }
}

extern "C" void kernel_launch(void* const* d_in, const int* in_sizes, int n_in,
                              void* d_out, int out_size, void* d_ws, size_t ws_size,
                              hipStream_t stream) {
    const float* enc = (const float*)d_in[0];   // [4,4096,1024]
    const float* dec = (const float*)d_in[1];   // [4,2048,1024]
    const float* Wq  = (const float*)d_in[2];
    const float* bq  = (const float*)d_in[3];
    const float* Wk  = (const float*)d_in[4];
    const float* bk  = (const float*)d_in[5];
    const float* Wv  = (const float*)d_in[6];
    const float* bv  = (const float*)d_in[7];

    char* ws = (char*)d_ws;
    u16* wtq   = (u16*)(ws + WTQ_OFF);
    u16* wtkv  = (u16*)(ws + WTKV_OFF);
    u16* Qb    = (u16*)(ws + Q_OFF);
    u16* Kb    = (u16*)(ws + K_OFF);
    u16* Vtb   = (u16*)(ws + VT_OFF);
    float* OpT = (float*)(ws + OPT_OFF);

    prep2<<<48, 256, 0, stream>>>(Wq, Wk, Wv, wtq, wtkv);
    proj5<<<384, 256, 0, stream>>>(enc, dec, wtkv, wtq, bk, bv, bq, Kb, Vtb, Qb);

    const size_t need8 = (size_t)OPT_OFF + 8ull * 4 * 64 * 2048 * 4 + 2ull * 8 * 8192 * 4;
    if (ws_size >= need8) {
        float* Mpart = (float*)(ws + OPT_OFF + 8ull * 4 * 64 * 2048 * 4);
        float* Lpart = Mpart + 8 * 8192;
        attn3<8><<<dim3(16, 4, 8), 256, 0, stream>>>(Qb, Kb, Vtb, OpT, Mpart, Lpart);
        combine3<8><<<256, 256, 0, stream>>>(OpT, Mpart, Lpart, (float*)d_out);
    } else {
        float* Mpart = (float*)(ws + OPT_OFF + 4ull * 4 * 64 * 2048 * 4);
        float* Lpart = Mpart + 4 * 8192;
        attn3<4><<<dim3(16, 4, 4), 256, 0, stream>>>(Qb, Kb, Vtb, OpT, Mpart, Lpart);
        combine3<4><<<256, 256, 0, stream>>>(OpT, Mpart, Lpart, (float*)d_out);
    }
}